// Round 8
// baseline (64.813 us; speedup 1.0000x reference)
//
#include <hip/hip_runtime.h>

#define B_   8192
#define DIN  512
#define DOUT 512
#define NC   8
#define NCD  (NC * DIN)
#define KSPL 4

typedef float  f32x4 __attribute__((ext_vector_type(4)));
typedef short  s16x8 __attribute__((ext_vector_type(8)));
typedef unsigned short u16x4 __attribute__((ext_vector_type(4)));
typedef unsigned int   u32x4 __attribute__((ext_vector_type(4)));

__device__ __forceinline__ unsigned short f2bf(float f) {
  unsigned u = __builtin_bit_cast(unsigned, f);
  u += 0x7fffu + ((u >> 16) & 1u);          // RTNE
  return (unsigned short)(u >> 16);
}
__device__ __forceinline__ float bf2f(unsigned short h) {
  unsigned u = ((unsigned)h) << 16;
  return __builtin_bit_cast(float, u);
}
__device__ __forceinline__ unsigned cvtpk(float lo, float hi) {
  unsigned r;
  asm("v_cvt_pk_bf16_f32 %0, %1, %2" : "=v"(r) : "v"(lo), "v"(hi));
  return r;
}
__device__ __forceinline__ void gl2lds16(const void* g, void* l) {
  __builtin_amdgcn_global_load_lds(
      (const __attribute__((address_space(1))) void*)g,
      (__attribute__((address_space(3))) void*)l, 16, 0, 0);
}

// ---------- fused pack: x (f32->bf16) and w (f32 transpose->bf16) ----------
__global__ void pack_xw_k(const f32x4* __restrict__ x, u16x4* __restrict__ xb,
                          const float* __restrict__ w, unsigned short* __restrict__ Wt) {
  __shared__ float tile[64][65];
  const int tid = threadIdx.x;
  if (blockIdx.x < 4096) {                      // pack x: 4096 blocks
    int gid = blockIdx.x * 256 + tid;
    f32x4 v = x[gid];
    u16x4 o;
    o[0] = f2bf(v[0]); o[1] = f2bf(v[1]); o[2] = f2bf(v[2]); o[3] = f2bf(v[3]);
    xb[gid] = o;
    return;
  }
  const int idx = blockIdx.x - 4096;            // pack w: 512 blocks
  const int kt = idx & 63, nt = idx >> 6;
#pragma unroll
  for (int it = 0; it < 16; ++it) {
    int u = it * 256 + tid;
    int r = u >> 6, cc = u & 63;
    tile[r][cc] = w[(size_t)(kt * 64 + r) * DOUT + nt * 64 + cc];
  }
  __syncthreads();
#pragma unroll
  for (int it = 0; it < 16; ++it) {
    int u = it * 256 + tid;
    int rn = u >> 6, ck = u & 63;
    Wt[(size_t)(nt * 64 + rn) * NCD + kt * 64 + ck] = f2bf(tile[ck][rn]);
  }
}

// ---- fused GEMM: part_s = (wt .* x) @ W', 256x256 tile, K=1024 (split-K 4) ----
// r8 schedule: ONE barrier/tile + 4-phase intra-tile interleave.
//   top:  vmcnt(4) [retires B(t); A(t+1) stays]; BAR; issue B(t+1)->ob
//   phi0: rd a(m0-3,kk0)+b(kk0) [8 rds]; MFMA q(m0-3,kk0)
//   phi1: rd a(m4-7,kk0)+b2(kk1) [8 rds]; MFMA q(m4-7,kk0)
//   phi2: rd a(m0-3,kk1) [4]; vmcnt(4) [A(t+1) landed; B(t+1) flies];
//         SCALE->ob; MFMA q(m0-3,kk1)
//   phi3: rd a(m4-7,kk1) [4]; AREGS(t+2); lgkm(0)+schedbar; MFMA q(m4-7,kk1)
// Safety of 1 barrier: stage into cb(t) is issued at top of t+1 AFTER the BAR
// that all cb-readers passed; each wave's ds_writes drained by its own
// lgkmcnt(0) before it reaches that BAR.  Single a[4] frag set reused per
// quadrant = WAR deps force read/MFMA interleave (no sched pragmas needed).
// vmcnt audit: issues/tile = [B4(t+1) after BAR, A4(t+2) in phi3] -> FIFO
// at top of t: {B4(t), A4(t+1)} = 8 -> vmcnt(4) retires B4(t);
// at phi2:     {A4(t+1), B4(t+1)} = 8 -> vmcnt(4) retires A4(t+1).
__global__ __launch_bounds__(512, 2) void gemm_k(
    const unsigned short* __restrict__ xb,   // [B_][DIN] bf16
    const unsigned short* __restrict__ Wt,   // [DOUT][NCD] bf16
    const float* __restrict__ wt,            // [B_][NC] f32
    unsigned short* __restrict__ part) {     // [KSPL][B_][DOUT] bf16
  extern __shared__ char smem[];
  const int tid  = threadIdx.x;
  const int lane = tid & 63, wid = tid >> 6;
  const int wm = wid >> 2, wn = wid & 3;       // 2 x 4 wave grid
  const int l15 = lane & 15, lhi = lane >> 4;

  const int n0   = blockIdx.x;                 // 256 blocks; xcd = n0&7 = (bx,ks)
  const int by   = n0 >> 3;                    // 0..31
  const int bx   = (n0 >> 2) & 1;              // 0..1
  const int ks   = n0 & 3;                     // K-chunk: experts 2ks, 2ks+1
  const int brow = by * 256, bcol = bx * 256;

  const int srow = tid >> 3, schunk = tid & 7;
  const int swz  = schunk ^ (srow & 7);
  const unsigned short* gA = xb + (size_t)(brow + srow) * DIN + schunk * 8; // linear src
  const unsigned short* gB = Wt + (size_t)(bcol + srow) * NCD + ks * 1024 + swz * 8;
  char* adst = smem + srow * 128 + swz * 16;   // + bufbase + p*8192

  // routing weights for this block's rows x 2 experts (held in VGPRs)
  const float* wtp = wt + (size_t)(brow + srow) * NC + ks * 2;
  const float wtv0_0 = wtp[0],            wtv1_0 = wtp[1];
  const float wtv0_1 = wtp[64 * NC],      wtv1_1 = wtp[64 * NC + 1];
  const float wtv0_2 = wtp[128 * NC],     wtv1_2 = wtp[128 * NC + 1];
  const float wtv0_3 = wtp[192 * NC],     wtv1_3 = wtp[192 * NC + 1];

  f32x4 acc[8][4] = {};
  s16x8 areg0, areg1, areg2, areg3;
  s16x8 a[4], b0q[4], b1q[4];
  const int x7    = l15 & 7;
  const int pc0   = (lhi ^ x7) * 16;           // phys chunk byte-offset, kk=0
  const int pc1   = ((4 + lhi) ^ x7) * 16;     // kk=1
  const int abase = (wm * 128 + l15) * 128;
  const int bbase = 32768 + (wn * 64 + l15) * 128;

#define STAGE_B(kt, ob) {                                                    \
    const unsigned short* s_ = gB + (size_t)(kt) * 64;                       \
    char* l_ = smem + (ob) + 32768 + tid * 16;                               \
    gl2lds16(s_,                          l_);                               \
    gl2lds16(s_ + (size_t) 64 * NCD,      l_ + 8192);                        \
    gl2lds16(s_ + (size_t)128 * NCD,      l_ + 16384);                       \
    gl2lds16(s_ + (size_t)192 * NCD,      l_ + 24576); }
#define LOAD_AREGS(kt) {                                                     \
    const unsigned short* s_ = gA + ((kt) & 7) * 64;                         \
    areg0 = *(const s16x8*)(s_);                                             \
    areg1 = *(const s16x8*)(s_ + (size_t) 64 * DIN);                         \
    areg2 = *(const s16x8*)(s_ + (size_t)128 * DIN);                         \
    areg3 = *(const s16x8*)(s_ + (size_t)192 * DIN); }
#define SCALE_STORE(AR, S, P, ob) {                                          \
    u32x4 v_;                                                                \
    v_[0] = cvtpk(bf2f((unsigned short)AR[0]) * (S),                         \
                  bf2f((unsigned short)AR[1]) * (S));                        \
    v_[1] = cvtpk(bf2f((unsigned short)AR[2]) * (S),                         \
                  bf2f((unsigned short)AR[3]) * (S));                        \
    v_[2] = cvtpk(bf2f((unsigned short)AR[4]) * (S),                         \
                  bf2f((unsigned short)AR[5]) * (S));                        \
    v_[3] = cvtpk(bf2f((unsigned short)AR[6]) * (S),                         \
                  bf2f((unsigned short)AR[7]) * (S));                        \
    *(u32x4*)(adst + (ob) + (P) * 8192) = v_; }
#define SCALE_WRITE_ALL(e_, ob) {                                            \
    SCALE_STORE(areg0, (e_) ? wtv1_0 : wtv0_0, 0, ob);                       \
    SCALE_STORE(areg1, (e_) ? wtv1_1 : wtv0_1, 1, ob);                       \
    SCALE_STORE(areg2, (e_) ? wtv1_2 : wtv0_2, 2, ob);                       \
    SCALE_STORE(areg3, (e_) ? wtv1_3 : wtv0_3, 3, ob); }
#define RD_A(cbase, MOFF, PC) {                                              \
    const char* p_ = smem + (cbase) + abase + (PC);                          \
    a[0] = *(const s16x8*)(p_ + ((MOFF) + 0) * 2048);                        \
    a[1] = *(const s16x8*)(p_ + ((MOFF) + 1) * 2048);                        \
    a[2] = *(const s16x8*)(p_ + ((MOFF) + 2) * 2048);                        \
    a[3] = *(const s16x8*)(p_ + ((MOFF) + 3) * 2048); }
#define RD_B(cbase, PC, BQ) {                                                \
    const char* p_ = smem + (cbase) + bbase + (PC);                          \
    BQ[0] = *(const s16x8*)(p_);                                             \
    BQ[1] = *(const s16x8*)(p_ + 2048);                                      \
    BQ[2] = *(const s16x8*)(p_ + 4096);                                      \
    BQ[3] = *(const s16x8*)(p_ + 6144); }
#define MFMA_Q(MOFF, BQ)                                                     \
    _Pragma("unroll") for (int j = 0; j < 4; ++j)                            \
      _Pragma("unroll") for (int n = 0; n < 4; ++n)                          \
        acc[(MOFF) + j][n] = __builtin_amdgcn_mfma_f32_16x16x32_bf16(        \
            a[j], BQ[n], acc[(MOFF) + j][n], 0, 0, 0);
#define BAR()   __builtin_amdgcn_s_barrier()
#define PRIO1() __builtin_amdgcn_s_setprio(1)
#define PRIO0() __builtin_amdgcn_s_setprio(0)
#define PIN()   asm volatile("" ::: "memory")

  // ---- prologue: wt+A(0) loads, B(0) staged; scale As(0); A(1) in flight ----
  PIN();                          // wt loads pinned before A(0) (queue order)
  LOAD_AREGS(0);
  PIN();                          // A(0) before B(0)
  STAGE_B(0, 0);
  asm volatile("s_waitcnt vmcnt(4)" ::: "memory");   // wt + A(0) retired; B(0) flying
  SCALE_WRITE_ALL(0, 0);
  LOAD_AREGS(1);
  asm volatile("s_waitcnt lgkmcnt(0)" ::: "memory"); // As(0) writes drained

  for (int t = 0; t < 16; ++t) {
    const int cb = (t & 1) * 65536, ob = 65536 - cb;
    if (t < 15) {
      asm volatile("s_waitcnt vmcnt(4)" ::: "memory");  // B(t) landed; A(t+1) flies
    } else {
      asm volatile("s_waitcnt vmcnt(0)" ::: "memory");  // drain tail
    }
    BAR();                                              // cb visible; ob free
    if (t < 15) STAGE_B(t + 1, ob);
    // ---- phi0 ----
    RD_A(cb, 0, pc0); RD_B(cb, pc0, b0q);
    PRIO1(); MFMA_Q(0, b0q); PRIO0();
    // ---- phi1 ----
    RD_A(cb, 4, pc0); RD_B(cb, pc1, b1q);
    PRIO1(); MFMA_Q(4, b0q); PRIO0();
    // ---- phi2 ----
    RD_A(cb, 0, pc1);
    if (t < 15) {
      asm volatile("s_waitcnt vmcnt(4)" ::: "memory");  // A(t+1) landed
      const int e = ((t + 1) >> 3) & 1;
      SCALE_WRITE_ALL(e, ob);
    }
    PRIO1(); MFMA_Q(0, b1q); PRIO0();
    // ---- phi3 ----
    RD_A(cb, 4, pc1);
    if (t < 14) LOAD_AREGS(t + 2);
    asm volatile("s_waitcnt lgkmcnt(0)" ::: "memory");  // own ds_writes + reads done
    __builtin_amdgcn_sched_barrier(0);                  // rule #18: keep MFMA below
    PRIO1(); MFMA_Q(4, b1q); PRIO0();
  }

  // ---- epilogue: repack via LDS, then full-line dwordx4 stores ----
  __syncthreads();
  unsigned short* Cs = (unsigned short*)smem;   // [256][264] bf16
#pragma unroll
  for (int m = 0; m < 8; ++m)
#pragma unroll
    for (int n = 0; n < 4; ++n) {
      const int row = wm * 128 + m * 16 + lhi * 4;
      const int col = wn * 64 + n * 16 + l15;
      f32x4 v = acc[m][n];
#pragma unroll
      for (int j = 0; j < 4; ++j)
        Cs[(row + j) * 264 + col] = f2bf(v[j]);
    }
  __syncthreads();
  unsigned short* pc = part + (size_t)ks * (B_ * DOUT) + (size_t)brow * DOUT + bcol;
#pragma unroll
  for (int it = 0; it < 16; ++it) {
    const int u = it * 512 + tid;
    const int row = u >> 5, cu = (u & 31) * 8;
    f32x4 v = *(const f32x4*)(Cs + row * 264 + cu);
    *(f32x4*)(pc + (size_t)row * DOUT + cu) = v;
  }
#undef STAGE_B
#undef LOAD_AREGS
#undef SCALE_STORE
#undef SCALE_WRITE_ALL
#undef RD_A
#undef RD_B
#undef MFMA_Q
#undef BAR
#undef PRIO1
#undef PRIO0
#undef PIN
}

// -------- reduce: out = sum_s part_s + sum_c wt[b][c]*bias[c] --------
__global__ void reduce_k(const unsigned short* __restrict__ part,
                         const float* __restrict__ wt,
                         const float* __restrict__ bias,
                         float* __restrict__ out) {
  int gid = blockIdx.x * 256 + threadIdx.x;
  int b = gid >> 7;
  int o4 = (gid & 127) << 2;
  float w8[8];
  *(f32x4*)w8       = *(const f32x4*)(wt + (size_t)b * NC);
  *(f32x4*)(w8 + 4) = *(const f32x4*)(wt + (size_t)b * NC + 4);
  f32x4 acc = {0.f, 0.f, 0.f, 0.f};
  const size_t off = (size_t)b * DOUT + o4;
#pragma unroll
  for (int s = 0; s < KSPL; ++s) {
    u16x4 p = *(const u16x4*)(part + (size_t)s * (B_ * DOUT) + off);
#pragma unroll
    for (int i = 0; i < 4; ++i) acc[i] += bf2f(p[i]);
  }
#pragma unroll
  for (int cc = 0; cc < NC; ++cc) {
    f32x4 bi = *(const f32x4*)(bias + cc * DOUT + o4);
#pragma unroll
    for (int i = 0; i < 4; ++i) acc[i] += w8[cc] * bi[i];
  }
  *(f32x4*)(out + off) = acc;
}

// ---------------- fallback if ws too small ----------------
__global__ void bias_only_k(const float* __restrict__ wt,
                            const float* __restrict__ bias,
                            float* __restrict__ out) {
  int gid = blockIdx.x * 256 + threadIdx.x;
  int b = gid >> 7;
  int o4 = (gid & 127) << 2;
  float w8[8];
  *(f32x4*)w8       = *(const f32x4*)(wt + (size_t)b * NC);
  *(f32x4*)(w8 + 4) = *(const f32x4*)(wt + (size_t)b * NC + 4);
  f32x4 acc = {0.f, 0.f, 0.f, 0.f};
#pragma unroll
  for (int cc = 0; cc < NC; ++cc) {
    f32x4 bi = *(const f32x4*)(bias + cc * DOUT + o4);
#pragma unroll
    for (int i = 0; i < 4; ++i) acc[i] += w8[cc] * bi[i];
  }
  *(f32x4*)(out + (size_t)b * DOUT + o4) = acc;
}

extern "C" void kernel_launch(void* const* d_in, const int* in_sizes, int n_in,
                              void* d_out, int out_size, void* d_ws, size_t ws_size,
                              hipStream_t stream) {
  const float *x = nullptr, *wtc = nullptr, *w = nullptr, *bias = nullptr;
  for (int i = 0; i < n_in; ++i) {
    switch (in_sizes[i]) {
      case B_ * DIN:        x    = (const float*)d_in[i]; break;
      case B_ * NC:         wtc  = (const float*)d_in[i]; break;
      case NC * DIN * DOUT: w    = (const float*)d_in[i]; break;
      case NC * DOUT:       bias = (const float*)d_in[i]; break;
    }
  }
  float* out = (float*)d_out;

  const size_t XB_ELEMS   = (size_t)B_ * DIN;
  const size_t WT_ELEMS   = (size_t)DOUT * NCD;
  const size_t PART_ELEMS = (size_t)KSPL * B_ * DOUT;
  const size_t need = (XB_ELEMS + WT_ELEMS + PART_ELEMS) * sizeof(unsigned short);

  if (ws_size < need) {
    bias_only_k<<<(B_ * DOUT / 4) / 256, 256, 0, stream>>>(wtc, bias, out);
    return;
  }

  unsigned short* xb   = (unsigned short*)d_ws;
  unsigned short* Wt   = xb + XB_ELEMS;
  unsigned short* part = Wt + WT_ELEMS;

  const int GEMM_LDS = 256 * 264 * 2;   // 135168 B (staging uses first 131072)
  (void)hipFuncSetAttribute((const void*)gemm_k,
                            hipFuncAttributeMaxDynamicSharedMemorySize, GEMM_LDS);

  pack_xw_k<<<4096 + 512, 256, 0, stream>>>((const f32x4*)x, (u16x4*)xb, w, Wt);
  gemm_k<<<256, 512, GEMM_LDS, stream>>>(xb, Wt, wtc, part);
  reduce_k<<<(B_ * DOUT / 4) / 256, 256, 0, stream>>>(part, wtc, bias, out);
}